// Round 1
// baseline (1135.149 us; speedup 1.0000x reference)
//
#include <hip/hip_runtime.h>
#include <math.h>

#define NNODES 100000
#define NEDGES 3200000
#define NGRAPHS 512

// ---------- CSR build ----------

__global__ void csr_init_kernel(int* __restrict__ cnt,
                                float* __restrict__ pool, float* __restrict__ counts) {
    int i = blockIdx.x * blockDim.x + threadIdx.x;
    if (i < NNODES) cnt[i] = 0;
    if (i < NGRAPHS * 32) pool[i] = 0.0f;
    if (i < NGRAPHS) counts[i] = 0.0f;
}

__global__ void count_deg_kernel(const int* __restrict__ ei, int* __restrict__ cnt) {
    int e = blockIdx.x * blockDim.x + threadIdx.x;
    if (e >= NEDGES) return;
    atomicAdd(cnt + ei[NEDGES + e], 1);
}

__global__ void scan_kernel(const int* __restrict__ cnt, int* __restrict__ rowptr,
                            int* __restrict__ cursor) {
    __shared__ int ssum[1024];
    const int CH = (NNODES + 1023) / 1024;
    int t = threadIdx.x;
    int base = t * CH;
    int local = 0;
    for (int i = 0; i < CH; ++i) {
        int idx = base + i;
        if (idx < NNODES) local += cnt[idx];
    }
    ssum[t] = local;
    __syncthreads();
    for (int o = 1; o < 1024; o <<= 1) {
        int vv = (t >= o) ? ssum[t - o] : 0;
        __syncthreads();
        ssum[t] += vv;
        __syncthreads();
    }
    int run = (t > 0) ? ssum[t - 1] : 0;
    for (int i = 0; i < CH; ++i) {
        int idx = base + i;
        if (idx < NNODES) {
            rowptr[idx] = run;
            cursor[idx] = run;
            run += cnt[idx];
        }
    }
    if (t == 1023) rowptr[NNODES] = ssum[1023];
}

__global__ void scatter_kernel(const int* __restrict__ ei, int* __restrict__ cursor,
                               int* __restrict__ col) {
    int e = blockIdx.x * blockDim.x + threadIdx.x;
    if (e >= NEDGES) return;
    int s = ei[e];
    int d = ei[NEDGES + e];
    int pos = atomicAdd(cursor + d, 1);
    col[pos] = s;
}

// ---------- fused 4x linear: q, kv (packed), skip ----------

template<int DIN, int DOUT>
__global__ void linear4_kernel(const float* __restrict__ x,
                               const float* __restrict__ Wq, const float* __restrict__ bq,
                               const float* __restrict__ Wk, const float* __restrict__ bk,
                               const float* __restrict__ Wv, const float* __restrict__ bv,
                               const float* __restrict__ Ws, const float* __restrict__ bs,
                               float* __restrict__ q, float* __restrict__ kv,
                               float* __restrict__ s) {
    __shared__ float sW[4][DIN * DOUT];
    __shared__ float sB[4][DOUT];
    const float* Wp[4] = {Wq, Wk, Wv, Ws};
    const float* Bp[4] = {bq, bk, bv, bs};
    for (int m = 0; m < 4; ++m) {
        for (int i = threadIdx.x; i < DIN * DOUT; i += blockDim.x) sW[m][i] = Wp[m][i];
        for (int i = threadIdx.x; i < DOUT; i += blockDim.x) sB[m][i] = Bp[m][i];
    }
    __syncthreads();
    int n = blockIdx.x * blockDim.x + threadIdx.x;
    if (n >= NNODES) return;

    float xr[DIN];
    #pragma unroll
    for (int i = 0; i < DIN; ++i) xr[i] = x[(size_t)n * DIN + i];

    // m=0 -> q, m=1 -> kv[0:D], m=2 -> kv[D:2D], m=3 -> skip
    float* outp[4] = {q + (size_t)n * DOUT,
                      kv + (size_t)n * 2 * DOUT,
                      kv + (size_t)n * 2 * DOUT + DOUT,
                      s + (size_t)n * DOUT};
    #pragma unroll
    for (int m = 0; m < 4; ++m) {
        float* op = outp[m];
        #pragma unroll
        for (int j = 0; j < DOUT; j += 4) {
            float4 acc = make_float4(sB[m][j], sB[m][j + 1], sB[m][j + 2], sB[m][j + 3]);
            #pragma unroll
            for (int i = 0; i < DIN; ++i) {
                float xv = xr[i];
                acc.x += xv * sW[m][i * DOUT + j];
                acc.y += xv * sW[m][i * DOUT + j + 1];
                acc.z += xv * sW[m][i * DOUT + j + 2];
                acc.w += xv * sW[m][i * DOUT + j + 3];
            }
            *(float4*)(op + j) = acc;
        }
    }
}

// ---------- channel-vectorized gather attention (one wave per node) ----------
// Lane = [edge-group g][channel-quad l]; LPE = D/4 lanes per edge,
// G = 64/LPE edges per wave-iteration, LPE iterations cover a 64-edge chunk.
// Restructured for MLP: per chunk, phase 1 loads all src indices directly
// (no colv->shfl dependency), phase 2 issues ALL kv gathers into register
// arrays (up to 2*LPE independent dwordx4 loads in flight), phase 3 does
// pipelined score reductions, phase 4 the short serial online-softmax chain.
// Wave-uniform `it*G < navail` skips unneeded iterations (avg deg 32 < 64).

template<int D, bool POOL>
__global__ __launch_bounds__(256) void gather_attn_kernel(
    const int* __restrict__ rowptr, const int* __restrict__ col,
    const float* __restrict__ q, const float* __restrict__ kv,
    const float* __restrict__ sk, const int* __restrict__ batch,
    float* __restrict__ out, float* __restrict__ pool, float* __restrict__ counts) {
    constexpr int LPE = D / 4;        // lanes per edge (channel-quads)
    constexpr int G = 64 / LPE;       // edges per iteration
    int n = blockIdx.x * 4 + (threadIdx.x >> 6);
    if (n >= NNODES) return;
    int lane = threadIdx.x & 63;
    int l = lane & (LPE - 1);         // channel-quad id
    int g = lane / LPE;               // edge-group id
    int rs = rowptr[n], re = rowptr[n + 1];
    // wave-uniform by construction -> force scalar for branch/addr efficiency
    rs = __builtin_amdgcn_readfirstlane(rs);
    re = __builtin_amdgcn_readfirstlane(re);

    float4 qc = *(const float4*)(q + (size_t)n * D + 4 * l);
    float m = -INFINITY, den = 0.0f;
    float4 acc = make_float4(0.0f, 0.0f, 0.0f, 0.0f);
    constexpr float scale = (D == 16) ? 0.25f : 0.17677669529663687f;

    for (int base = rs; base < re; base += 64) {
        int navail = re - base;
        if (navail > 64) navail = 64;

        // phase 1: src indices, issued immediately (LPE lanes share an
        // address -> broadcast in the coalescer; clamped tail reads col[rs])
        int srcs[LPE];
        #pragma unroll
        for (int it = 0; it < LPE; ++it) {
            if (it * G < navail) {
                int idx = base + it * G + g;
                srcs[it] = col[idx < re ? idx : rs];
            }
        }

        // phase 2: all kv gathers for the chunk, independent, in flight at once
        float4 kk[LPE], vv[LPE];
        #pragma unroll
        for (int it = 0; it < LPE; ++it) {
            if (it * G < navail) {
                const float* kvp = kv + (size_t)srcs[it] * (2 * D);
                kk[it] = *(const float4*)(kvp + 4 * l);
                vv[it] = *(const float4*)(kvp + D + 4 * l);
            } else {
                kk[it] = make_float4(0.0f, 0.0f, 0.0f, 0.0f);
                vv[it] = make_float4(0.0f, 0.0f, 0.0f, 0.0f);  // keep 0*vv finite
            }
        }

        // phase 3: scores, shfl-reduce pipelined across iterations
        float p[LPE];
        #pragma unroll
        for (int it = 0; it < LPE; ++it) {
            float pp = qc.x * kk[it].x + qc.y * kk[it].y +
                       qc.z * kk[it].z + qc.w * kk[it].w;
            #pragma unroll
            for (int o = 1; o < LPE; o <<= 1) pp += __shfl_xor(pp, o, 64);
            p[it] = pp;
        }

        // phase 4: serial online-softmax chain on register data
        #pragma unroll
        for (int it = 0; it < LPE; ++it) {
            bool act = (it * G + g) < navail;
            float sc = act ? p[it] * scale : -INFINITY;
            float mn = fmaxf(m, sc);
            float r = (mn > m) ? __expf(m - mn) : 1.0f;  // m=-inf & sc>-inf -> 0
            float w = act ? __expf(sc - mn) : 0.0f;
            m = mn;
            den = den * r + w;
            acc.x = acc.x * r + w * vv[it].x;
            acc.y = acc.y * r + w * vv[it].y;
            acc.z = acc.z * r + w * vv[it].z;
            acc.w = acc.w * r + w * vv[it].w;
        }
    }

    // combine the G edge-groups across lane strides LPE..32
    #pragma unroll
    for (int o = LPE; o < 64; o <<= 1) {
        float mo = __shfl_xor(m, o, 64);
        float M = fmaxf(m, mo);
        float r = (m > -INFINITY) ? __expf(m - M) : 0.0f;
        float ds = den * r;
        float ax = acc.x * r, ay = acc.y * r, az = acc.z * r, aw = acc.w * r;
        den = ds + __shfl_xor(ds, o, 64);
        acc.x = ax + __shfl_xor(ax, o, 64);
        acc.y = ay + __shfl_xor(ay, o, 64);
        acc.z = az + __shfl_xor(az, o, 64);
        acc.w = aw + __shfl_xor(aw, o, 64);
        m = M;
    }

    if (g == 0) {
        float inv = 1.0f / fmaxf(den, 1e-16f);
        float4 s4 = *(const float4*)(sk + (size_t)n * D + 4 * l);
        float4 o_;
        o_.x = fmaxf(acc.x * inv + s4.x, 0.0f);
        o_.y = fmaxf(acc.y * inv + s4.y, 0.0f);
        o_.z = fmaxf(acc.z * inv + s4.z, 0.0f);
        o_.w = fmaxf(acc.w * inv + s4.w, 0.0f);
        if (POOL) {
            int b = batch[n];
            atomicAdd(pool + (size_t)b * D + 4 * l + 0, o_.x);
            atomicAdd(pool + (size_t)b * D + 4 * l + 1, o_.y);
            atomicAdd(pool + (size_t)b * D + 4 * l + 2, o_.z);
            atomicAdd(pool + (size_t)b * D + 4 * l + 3, o_.w);
            if (l == 0) atomicAdd(counts + b, 1.0f);
        } else {
            *(float4*)(out + (size_t)n * D + 4 * l) = o_;
        }
    }
}

// ---------- FC head ----------

__global__ void final_fc_kernel(const float* __restrict__ pool,
                                const float* __restrict__ counts,
                                const float* __restrict__ Wfc1, const float* __restrict__ bfc1,
                                const float* __restrict__ Wfc2, const float* __restrict__ bfc2,
                                float* __restrict__ out) {
    __shared__ float sW1[32 * 64];
    __shared__ float sB1[64];
    __shared__ float sW2[64];
    for (int i = threadIdx.x; i < 32 * 64; i += blockDim.x) sW1[i] = Wfc1[i];
    for (int i = threadIdx.x; i < 64; i += blockDim.x) { sB1[i] = bfc1[i]; sW2[i] = Wfc2[i]; }
    __syncthreads();
    int g = blockIdx.x * blockDim.x + threadIdx.x;
    if (g >= NGRAPHS) return;
    float c = fmaxf(counts[g], 1.0f);
    float gv[32];
    #pragma unroll
    for (int i = 0; i < 32; ++i) gv[i] = pool[(size_t)g * 32 + i] / c;
    float acc2 = bfc2[0];
    #pragma unroll
    for (int j = 0; j < 64; ++j) {
        float h = sB1[j];
        #pragma unroll
        for (int i = 0; i < 32; ++i) h += gv[i] * sW1[i * 64 + j];
        acc2 += fmaxf(h, 0.0f) * sW2[j];
    }
    out[g] = acc2;
}

// ---------- launch ----------

extern "C" void kernel_launch(void* const* d_in, const int* in_sizes, int n_in,
                              void* d_out, int out_size, void* d_ws, size_t ws_size,
                              hipStream_t stream) {
    const float* x     = (const float*)d_in[0];
    const int*   ei    = (const int*)d_in[1];
    const int*   batch = (const int*)d_in[2];
    const float* Wq1 = (const float*)d_in[3];  const float* bq1 = (const float*)d_in[4];
    const float* Wk1 = (const float*)d_in[5];  const float* bk1 = (const float*)d_in[6];
    const float* Wv1 = (const float*)d_in[7];  const float* bv1 = (const float*)d_in[8];
    const float* Ws1 = (const float*)d_in[9];  const float* bs1 = (const float*)d_in[10];
    const float* Wq2 = (const float*)d_in[11]; const float* bq2 = (const float*)d_in[12];
    const float* Wk2 = (const float*)d_in[13]; const float* bk2 = (const float*)d_in[14];
    const float* Wv2 = (const float*)d_in[15]; const float* bv2 = (const float*)d_in[16];
    const float* Ws2 = (const float*)d_in[17]; const float* bs2 = (const float*)d_in[18];
    const float* Wfc1 = (const float*)d_in[19]; const float* bfc1 = (const float*)d_in[20];
    const float* Wfc2 = (const float*)d_in[21]; const float* bfc2 = (const float*)d_in[22];
    float* out = (float*)d_out;

    char* wsb = (char*)d_ws;
    size_t off = 0;
    auto alloc = [&](size_t bytes) {
        void* p = wsb + off;
        off += (bytes + 255) & ~(size_t)255;
        return p;
    };
    float* q      = (float*)alloc((size_t)NNODES * 32 * 4);
    float* kv     = (float*)alloc((size_t)NNODES * 64 * 4);  // packed [k|v]
    float* sk     = (float*)alloc((size_t)NNODES * 32 * 4);
    float* h1     = (float*)alloc((size_t)NNODES * 16 * 4);
    int*   cnt    = (int*)alloc((size_t)NNODES * 4);
    int*   rowptr = (int*)alloc((size_t)(NNODES + 1) * 4);
    int*   cursor = (int*)alloc((size_t)NNODES * 4);
    int*   col    = (int*)alloc((size_t)NEDGES * 4);
    float* pool   = (float*)alloc((size_t)NGRAPHS * 32 * 4);
    float* counts = (float*)alloc((size_t)NGRAPHS * 4);

    const int B = 256;
    const int gridN = (NNODES + B - 1) / B;
    const int gridE = (NEDGES + B - 1) / B;
    const int gridW = (NNODES + 3) / 4;   // one 64-lane wave per node, 4 waves/block

    // ----- CSR build (by destination), shared by both layers -----
    csr_init_kernel<<<gridN, B, 0, stream>>>(cnt, pool, counts);
    count_deg_kernel<<<gridE, B, 0, stream>>>(ei, cnt);
    scan_kernel<<<1, 1024, 0, stream>>>(cnt, rowptr, cursor);
    scatter_kernel<<<gridE, B, 0, stream>>>(ei, cursor, col);

    // ----- layer 1 (d=16) -----
    linear4_kernel<11, 16><<<gridN, B, 0, stream>>>(x, Wq1, bq1, Wk1, bk1, Wv1, bv1, Ws1, bs1,
                                                    q, kv, sk);
    gather_attn_kernel<16, false><<<gridW, B, 0, stream>>>(rowptr, col, q, kv, sk, batch,
                                                           h1, nullptr, nullptr);

    // ----- layer 2 (d=32) -----
    linear4_kernel<16, 32><<<gridN, B, 0, stream>>>(h1, Wq2, bq2, Wk2, bk2, Wv2, bv2, Ws2, bs2,
                                                    q, kv, sk);
    gather_attn_kernel<32, true><<<gridW, B, 0, stream>>>(rowptr, col, q, kv, sk, batch,
                                                          nullptr, pool, counts);

    // ----- head -----
    final_fc_kernel<<<1, 512, 0, stream>>>(pool, counts, Wfc1, bfc1, Wfc2, bfc2, out);
}

// Round 2
// 1081.673 us; speedup vs baseline: 1.0494x; 1.0494x over previous
//
#include <hip/hip_runtime.h>
#include <hip/hip_fp16.h>
#include <math.h>

#define NNODES 100000
#define NEDGES 3200000
#define NGRAPHS 512

// ---------- CSR build ----------

__global__ void csr_init_kernel(int* __restrict__ cnt,
                                float* __restrict__ pool, float* __restrict__ counts) {
    int i = blockIdx.x * blockDim.x + threadIdx.x;
    if (i < NNODES) cnt[i] = 0;
    if (i < NGRAPHS * 32) pool[i] = 0.0f;
    if (i < NGRAPHS) counts[i] = 0.0f;
}

__global__ void count_deg_kernel(const int* __restrict__ ei, int* __restrict__ cnt) {
    int e = blockIdx.x * blockDim.x + threadIdx.x;
    if (e >= NEDGES) return;
    atomicAdd(cnt + ei[NEDGES + e], 1);
}

__global__ void scan_kernel(const int* __restrict__ cnt, int* __restrict__ rowptr,
                            int* __restrict__ cursor) {
    __shared__ int ssum[1024];
    const int CH = (NNODES + 1023) / 1024;
    int t = threadIdx.x;
    int base = t * CH;
    int local = 0;
    for (int i = 0; i < CH; ++i) {
        int idx = base + i;
        if (idx < NNODES) local += cnt[idx];
    }
    ssum[t] = local;
    __syncthreads();
    for (int o = 1; o < 1024; o <<= 1) {
        int vv = (t >= o) ? ssum[t - o] : 0;
        __syncthreads();
        ssum[t] += vv;
        __syncthreads();
    }
    int run = (t > 0) ? ssum[t - 1] : 0;
    for (int i = 0; i < CH; ++i) {
        int idx = base + i;
        if (idx < NNODES) {
            rowptr[idx] = run;
            cursor[idx] = run;
            run += cnt[idx];
        }
    }
    if (t == 1023) rowptr[NNODES] = ssum[1023];
}

__global__ void scatter_kernel(const int* __restrict__ ei, int* __restrict__ cursor,
                               int* __restrict__ col) {
    int e = blockIdx.x * blockDim.x + threadIdx.x;
    if (e >= NEDGES) return;
    int s = ei[e];
    int d = ei[NEDGES + e];
    int pos = atomicAdd(cursor + d, 1);
    col[pos] = s;
}

// ---------- fused 4x linear: q (f32), kv packed (f16), skip (f32) ----------

template<int DIN, int DOUT>
__global__ void linear4_kernel(const float* __restrict__ x,
                               const float* __restrict__ Wq, const float* __restrict__ bq,
                               const float* __restrict__ Wk, const float* __restrict__ bk,
                               const float* __restrict__ Wv, const float* __restrict__ bv,
                               const float* __restrict__ Ws, const float* __restrict__ bs,
                               float* __restrict__ q, __half* __restrict__ kv,
                               float* __restrict__ s) {
    __shared__ float sW[4][DIN * DOUT];
    __shared__ float sB[4][DOUT];
    const float* Wp[4] = {Wq, Wk, Wv, Ws};
    const float* Bp[4] = {bq, bk, bv, bs};
    for (int m = 0; m < 4; ++m) {
        for (int i = threadIdx.x; i < DIN * DOUT; i += blockDim.x) sW[m][i] = Wp[m][i];
        for (int i = threadIdx.x; i < DOUT; i += blockDim.x) sB[m][i] = Bp[m][i];
    }
    __syncthreads();
    int n = blockIdx.x * blockDim.x + threadIdx.x;
    if (n >= NNODES) return;

    float xr[DIN];
    #pragma unroll
    for (int i = 0; i < DIN; ++i) xr[i] = x[(size_t)n * DIN + i];

    // m=0 -> q (f32), m=1 -> kv[0:D] (f16), m=2 -> kv[D:2D] (f16), m=3 -> skip (f32)
    #pragma unroll
    for (int m = 0; m < 4; ++m) {
        #pragma unroll
        for (int j = 0; j < DOUT; j += 4) {
            float4 acc = make_float4(sB[m][j], sB[m][j + 1], sB[m][j + 2], sB[m][j + 3]);
            #pragma unroll
            for (int i = 0; i < DIN; ++i) {
                float xv = xr[i];
                acc.x += xv * sW[m][i * DOUT + j];
                acc.y += xv * sW[m][i * DOUT + j + 1];
                acc.z += xv * sW[m][i * DOUT + j + 2];
                acc.w += xv * sW[m][i * DOUT + j + 3];
            }
            if (m == 0) {
                *(float4*)(q + (size_t)n * DOUT + j) = acc;
            } else if (m == 3) {
                *(float4*)(s + (size_t)n * DOUT + j) = acc;
            } else {
                __half* op = kv + (size_t)n * 2 * DOUT + (m == 1 ? 0 : DOUT) + j;
                *(__half2*)(op)     = __floats2half2_rn(acc.x, acc.y);
                *(__half2*)(op + 2) = __floats2half2_rn(acc.z, acc.w);
            }
        }
    }
}

// ---------- channel-vectorized gather attention (one wave per node) ----------
// Lane = [edge-group g][channel-quad l]; LPE = D/4 lanes per edge,
// G = 64/LPE edges per wave-iteration. kv packed [k row | v row] in FP16:
// d=32 row = 128B (one cache line), d=16 row = 64B -> halves the random
// gather traffic and shrinks the table for L2 residency.
// Fuses online softmax, weighted-V agg, combine+ReLU, and (POOL) pooling.

template<int D, bool POOL>
__global__ __launch_bounds__(256) void gather_attn_kernel(
    const int* __restrict__ rowptr, const int* __restrict__ col,
    const float* __restrict__ q, const __half* __restrict__ kv,
    const float* __restrict__ sk, const int* __restrict__ batch,
    float* __restrict__ out, float* __restrict__ pool, float* __restrict__ counts) {
    constexpr int LPE = D / 4;        // lanes per edge
    constexpr int G = 64 / LPE;       // edges per iteration
    int n = blockIdx.x * 4 + (threadIdx.x >> 6);
    if (n >= NNODES) return;
    int lane = threadIdx.x & 63;
    int l = lane & (LPE - 1);         // channel-quad id
    int g = lane / LPE;               // edge-group id
    int rs = rowptr[n], re = rowptr[n + 1];

    float4 qc = *(const float4*)(q + (size_t)n * D + 4 * l);
    float m = -INFINITY, den = 0.0f;
    float4 acc = make_float4(0.0f, 0.0f, 0.0f, 0.0f);
    constexpr float scale = (D == 16) ? 0.25f : 0.17677669529663687f;

    for (int base = rs; base < re; base += 64) {
        int navail = re - base;
        if (navail > 64) navail = 64;
        int colv = (lane < navail) ? col[base + lane] : 0;
        int iters = (navail + G - 1) / G;
        for (int it = 0; it < iters; ++it) {
            int slot = it * G + g;
            bool act = slot < navail;
            int src = __shfl(colv, slot, 64);
            const __half* kvrow = kv + (size_t)src * (2 * D);
            // lane's 4 k-channels and 4 v-channels: one 8B load each
            uint2 kraw = *(const uint2*)(kvrow + 4 * l);
            uint2 vraw = *(const uint2*)(kvrow + D + 4 * l);
            float2 k01 = __half22float2(*(__half2*)&kraw.x);
            float2 k23 = __half22float2(*(__half2*)&kraw.y);
            float2 v01 = __half22float2(*(__half2*)&vraw.x);
            float2 v23 = __half22float2(*(__half2*)&vraw.y);
            float p = qc.x * k01.x + qc.y * k01.y + qc.z * k23.x + qc.w * k23.y;
            #pragma unroll
            for (int o = 1; o < LPE; o <<= 1) p += __shfl_xor(p, o, 64);
            float sc = act ? p * scale : -INFINITY;
            float mn = fmaxf(m, sc);
            float r = (mn > m) ? __expf(m - mn) : 1.0f;  // m=-inf & sc>-inf -> 0
            float w = act ? __expf(sc - mn) : 0.0f;
            m = mn;
            den = den * r + w;
            acc.x = acc.x * r + w * v01.x;
            acc.y = acc.y * r + w * v01.y;
            acc.z = acc.z * r + w * v23.x;
            acc.w = acc.w * r + w * v23.y;
        }
    }

    // combine the G edge-groups across lane strides LPE..32
    #pragma unroll
    for (int o = LPE; o < 64; o <<= 1) {
        float mo = __shfl_xor(m, o, 64);
        float M = fmaxf(m, mo);
        float r = (m > -INFINITY) ? __expf(m - M) : 0.0f;
        float ds = den * r;
        float ax = acc.x * r, ay = acc.y * r, az = acc.z * r, aw = acc.w * r;
        den = ds + __shfl_xor(ds, o, 64);
        acc.x = ax + __shfl_xor(ax, o, 64);
        acc.y = ay + __shfl_xor(ay, o, 64);
        acc.z = az + __shfl_xor(az, o, 64);
        acc.w = aw + __shfl_xor(aw, o, 64);
        m = M;
    }

    if (g == 0) {
        float inv = 1.0f / fmaxf(den, 1e-16f);
        float4 s4 = *(const float4*)(sk + (size_t)n * D + 4 * l);
        float4 o_;
        o_.x = fmaxf(acc.x * inv + s4.x, 0.0f);
        o_.y = fmaxf(acc.y * inv + s4.y, 0.0f);
        o_.z = fmaxf(acc.z * inv + s4.z, 0.0f);
        o_.w = fmaxf(acc.w * inv + s4.w, 0.0f);
        if (POOL) {
            int b = batch[n];
            atomicAdd(pool + (size_t)b * D + 4 * l + 0, o_.x);
            atomicAdd(pool + (size_t)b * D + 4 * l + 1, o_.y);
            atomicAdd(pool + (size_t)b * D + 4 * l + 2, o_.z);
            atomicAdd(pool + (size_t)b * D + 4 * l + 3, o_.w);
            if (l == 0) atomicAdd(counts + b, 1.0f);
        } else {
            *(float4*)(out + (size_t)n * D + 4 * l) = o_;
        }
    }
}

// ---------- FC head ----------

__global__ void final_fc_kernel(const float* __restrict__ pool,
                                const float* __restrict__ counts,
                                const float* __restrict__ Wfc1, const float* __restrict__ bfc1,
                                const float* __restrict__ Wfc2, const float* __restrict__ bfc2,
                                float* __restrict__ out) {
    __shared__ float sW1[32 * 64];
    __shared__ float sB1[64];
    __shared__ float sW2[64];
    for (int i = threadIdx.x; i < 32 * 64; i += blockDim.x) sW1[i] = Wfc1[i];
    for (int i = threadIdx.x; i < 64; i += blockDim.x) { sB1[i] = bfc1[i]; sW2[i] = Wfc2[i]; }
    __syncthreads();
    int g = blockIdx.x * blockDim.x + threadIdx.x;
    if (g >= NGRAPHS) return;
    float c = fmaxf(counts[g], 1.0f);
    float gv[32];
    #pragma unroll
    for (int i = 0; i < 32; ++i) gv[i] = pool[(size_t)g * 32 + i] / c;
    float acc2 = bfc2[0];
    #pragma unroll
    for (int j = 0; j < 64; ++j) {
        float h = sB1[j];
        #pragma unroll
        for (int i = 0; i < 32; ++i) h += gv[i] * sW1[i * 64 + j];
        acc2 += fmaxf(h, 0.0f) * sW2[j];
    }
    out[g] = acc2;
}

// ---------- launch ----------

extern "C" void kernel_launch(void* const* d_in, const int* in_sizes, int n_in,
                              void* d_out, int out_size, void* d_ws, size_t ws_size,
                              hipStream_t stream) {
    const float* x     = (const float*)d_in[0];
    const int*   ei    = (const int*)d_in[1];
    const int*   batch = (const int*)d_in[2];
    const float* Wq1 = (const float*)d_in[3];  const float* bq1 = (const float*)d_in[4];
    const float* Wk1 = (const float*)d_in[5];  const float* bk1 = (const float*)d_in[6];
    const float* Wv1 = (const float*)d_in[7];  const float* bv1 = (const float*)d_in[8];
    const float* Ws1 = (const float*)d_in[9];  const float* bs1 = (const float*)d_in[10];
    const float* Wq2 = (const float*)d_in[11]; const float* bq2 = (const float*)d_in[12];
    const float* Wk2 = (const float*)d_in[13]; const float* bk2 = (const float*)d_in[14];
    const float* Wv2 = (const float*)d_in[15]; const float* bv2 = (const float*)d_in[16];
    const float* Ws2 = (const float*)d_in[17]; const float* bs2 = (const float*)d_in[18];
    const float* Wfc1 = (const float*)d_in[19]; const float* bfc1 = (const float*)d_in[20];
    const float* Wfc2 = (const float*)d_in[21]; const float* bfc2 = (const float*)d_in[22];
    float* out = (float*)d_out;

    char* wsb = (char*)d_ws;
    size_t off = 0;
    auto alloc = [&](size_t bytes) {
        void* p = wsb + off;
        off += (bytes + 255) & ~(size_t)255;
        return p;
    };
    float*  q      = (float*)alloc((size_t)NNODES * 32 * 4);
    __half* kv     = (__half*)alloc((size_t)NNODES * 64 * 2);  // packed [k|v], fp16
    float*  sk     = (float*)alloc((size_t)NNODES * 32 * 4);
    float*  h1     = (float*)alloc((size_t)NNODES * 16 * 4);
    int*    cnt    = (int*)alloc((size_t)NNODES * 4);
    int*    rowptr = (int*)alloc((size_t)(NNODES + 1) * 4);
    int*    cursor = (int*)alloc((size_t)NNODES * 4);
    int*    col    = (int*)alloc((size_t)NEDGES * 4);
    float*  pool   = (float*)alloc((size_t)NGRAPHS * 32 * 4);
    float*  counts = (float*)alloc((size_t)NGRAPHS * 4);

    const int B = 256;
    const int gridN = (NNODES + B - 1) / B;
    const int gridE = (NEDGES + B - 1) / B;
    const int gridW = (NNODES + 3) / 4;   // one 64-lane wave per node, 4 waves/block

    // ----- CSR build (by destination), shared by both layers -----
    csr_init_kernel<<<gridN, B, 0, stream>>>(cnt, pool, counts);
    count_deg_kernel<<<gridE, B, 0, stream>>>(ei, cnt);
    scan_kernel<<<1, 1024, 0, stream>>>(cnt, rowptr, cursor);
    scatter_kernel<<<gridE, B, 0, stream>>>(ei, cursor, col);

    // ----- layer 1 (d=16) -----
    linear4_kernel<11, 16><<<gridN, B, 0, stream>>>(x, Wq1, bq1, Wk1, bk1, Wv1, bv1, Ws1, bs1,
                                                    q, kv, sk);
    gather_attn_kernel<16, false><<<gridW, B, 0, stream>>>(rowptr, col, q, kv, sk, batch,
                                                           h1, nullptr, nullptr);

    // ----- layer 2 (d=32) -----
    linear4_kernel<16, 32><<<gridN, B, 0, stream>>>(h1, Wq2, bq2, Wk2, bk2, Wv2, bv2, Ws2, bs2,
                                                    q, kv, sk);
    gather_attn_kernel<32, true><<<gridW, B, 0, stream>>>(rowptr, col, q, kv, sk, batch,
                                                          nullptr, pool, counts);

    // ----- head -----
    final_fc_kernel<<<1, 512, 0, stream>>>(pool, counts, Wfc1, bfc1, Wfc2, bfc2, out);
}